// Round 3
// baseline (131.466 us; speedup 1.0000x reference)
//
#include <hip/hip_runtime.h>

typedef unsigned short u16;
typedef unsigned int   u32;
typedef unsigned long long u64;
typedef __attribute__((ext_vector_type(8))) __bf16 bf16x8;
typedef __attribute__((ext_vector_type(4))) float  f32x4;

#define NTOK 8192
#define HD   512
#define NEXP 8
#define NBLK 2048   // router blocks (4 tokens each)
#define NFB  128    // fill blocks (64 tokens each)

// ---- workspace byte offsets ----
#define WS_W1T    0ull
#define WS_W3T    4194304ull
#define WS_W2T    8388608ull
#define WS_XN     12582912ull   // 8192*512 bf16
#define WS_ACT    20971520ull   // (16384+128)*512 bf16
#define WS_YP     37879808ull   // 16384*512 f32
#define WS_PSUM   71434240ull   // [8][2048] f32
#define WS_BCNT   71499776ull   // [8][2048] int
#define WS_FBOFF  71565312ull   // [128][8] int
#define WS_GATES  71696384ull   // 16384 f32
#define WS_TOKOF  71761920ull   // 16384 int
#define WS_DESTOF 71827456ull   // 16384 int
#define WS_TOPE   71892992ull   // 16384 int
#define WS_CNT    71958528ull   // 8 int
#define WS_OFFS   71958592ull   // 8 int

static __device__ __forceinline__ u16 f2bf(float f) {
  u32 u = __builtin_bit_cast(u32, f);
  u = (u + 0x7fffu + ((u >> 16) & 1u)) >> 16;
  return (u16)u;
}

static __device__ __forceinline__ void gload16(const void* g, void* l) {
  __builtin_amdgcn_global_load_lds((const __attribute__((address_space(1))) void*)g,
                                   (__attribute__((address_space(3))) void*)l, 16, 0, 0);
}

// ---------------- weight prep: f32 [e][k][n] -> bf16 [e][n][k], LDS transpose ----------------
__global__ __launch_bounds__(256) void k_prep(
    const float* __restrict__ W1, const float* __restrict__ W3, const float* __restrict__ W2,
    u16* __restrict__ W1T, u16* __restrict__ W3T, u16* __restrict__ W2T)
{
  u32 b = blockIdx.x;             // 1536 blocks = 3 arrays * 8 experts * 64 tiles
  u32 a = b >> 9;
  u32 rem = b & 511u;
  u32 e = rem >> 6;
  u32 tile = rem & 63u;
  u32 tk = tile >> 3, tn = tile & 7;
  const float* s = ((a == 0) ? W1 : (a == 1) ? W3 : W2) + ((size_t)e << 18);
  u16* d = ((a == 0) ? W1T : (a == 1) ? W3T : W2T) + ((size_t)e << 18);
  __shared__ u16 tileS[64 * 70];
  int t = threadIdx.x;
  int r = t >> 4, c4 = t & 15;
#pragma unroll
  for (int i = 0; i < 4; i++) {
    int rr = r + i * 16;
    const float4 v = *(const float4*)(s + (size_t)(tk * 64 + rr) * 512 + tn * 64 + c4 * 4);
    u32 w0 = f2bf(v.x) | ((u32)f2bf(v.y) << 16);
    u32 w1 = f2bf(v.z) | ((u32)f2bf(v.w) << 16);
    u32* p = (u32*)&tileS[rr * 70 + c4 * 4];
    p[0] = w0; p[1] = w1;
  }
  __syncthreads();
  int n = t >> 3, kc = t & 7;
#pragma unroll
  for (int i = 0; i < 2; i++) {
    int nn = n + i * 32;
    u16 vals[8];
#pragma unroll
    for (int j = 0; j < 8; j++) vals[j] = tileS[(kc * 8 + j) * 70 + nn];
    *(uint4*)(d + (size_t)(tn * 64 + nn) * 512 + tk * 64 + kc * 8) = *(uint4*)vals;
  }
}

// ---------------- router + RMSNorm (no global atomics) ----------------
__global__ __launch_bounds__(256) void k_router(
    const float* __restrict__ x, const float* __restrict__ Wg,
    u16* __restrict__ xn, int* __restrict__ topE, float* __restrict__ gates,
    float* __restrict__ psum, int* __restrict__ bcnt)
{
  __shared__ float lp[4][8];
  __shared__ int lcnt[8];
  int t = threadIdx.x;
  if (t < 8) lcnt[t] = 0;
  __syncthreads();
  int lane = t & 63;
  int w = t >> 6;
  int n = blockIdx.x * 4 + w;
  const float4* xr = (const float4*)(x + (size_t)n * HD);
  float4 xa = xr[lane * 2], xb = xr[lane * 2 + 1];
  float xv[8] = {xa.x, xa.y, xa.z, xa.w, xb.x, xb.y, xb.z, xb.w};
  float ss = 0.f;
  float le[8] = {0.f, 0.f, 0.f, 0.f, 0.f, 0.f, 0.f, 0.f};
  int base = lane * 8;
#pragma unroll
  for (int j = 0; j < 8; j++) {
    float v = xv[j];
    ss += v * v;
    const float4* wg = (const float4*)(Wg + (size_t)(base + j) * NEXP);
    float4 w0 = wg[0], w1 = wg[1];
    le[0] += v * w0.x; le[1] += v * w0.y; le[2] += v * w0.z; le[3] += v * w0.w;
    le[4] += v * w1.x; le[5] += v * w1.y; le[6] += v * w1.z; le[7] += v * w1.w;
  }
#pragma unroll
  for (int s = 1; s < 64; s <<= 1) {
    ss += __shfl_xor(ss, s);
#pragma unroll
    for (int e = 0; e < 8; e++) le[e] += __shfl_xor(le[e], s);
  }
  float m = le[0];
#pragma unroll
  for (int e = 1; e < 8; e++) m = fmaxf(m, le[e]);
  float p[8]; float S = 0.f;
#pragma unroll
  for (int e = 0; e < 8; e++) { p[e] = __expf(le[e] - m); S += p[e]; }
  float inv = 1.f / S;
#pragma unroll
  for (int e = 0; e < 8; e++) p[e] *= inv;
  int i1 = 0;
#pragma unroll
  for (int e = 1; e < 8; e++) if (p[e] > p[i1]) i1 = e;
  int i2 = (i1 == 0) ? 1 : 0;
#pragma unroll
  for (int e = 0; e < 8; e++) if (e != i1 && p[e] > p[i2]) i2 = e;

  if (lane < 8) lp[w][lane] = p[lane];
  if (lane == 0) {
    topE[2 * n] = i1; topE[2 * n + 1] = i2;
    float gs = p[i1] + p[i2];
    gates[2 * n] = p[i1] / gs;
    gates[2 * n + 1] = p[i2] / gs;
    atomicAdd(&lcnt[i1], 1);   // LDS atomic: deterministic value
    atomicAdd(&lcnt[i2], 1);
  }
  float rinv = rsqrtf(ss * (1.f / 512.f) + 1e-8f);
  uint4 o;
  u32* op = (u32*)&o;
#pragma unroll
  for (int j = 0; j < 4; j++) {
    u32 lo = f2bf(xv[2 * j] * rinv);
    u32 hi = f2bf(xv[2 * j + 1] * rinv);
    op[j] = lo | (hi << 16);
  }
  ((uint4*)(xn + (size_t)n * HD))[lane] = o;
  __syncthreads();
  if (t < 8) {
    bcnt[t * NBLK + blockIdx.x] = lcnt[t];
    psum[t * NBLK + blockIdx.x] = ((lp[0][t] + lp[1][t]) + lp[2][t]) + lp[3][t];
  }
}

// ---------------- scan: counts, offsets, fill-block offsets, load_F ----------------
__global__ __launch_bounds__(256) void k_scan(
    const int* __restrict__ bcnt, const float* __restrict__ psum,
    int* __restrict__ cnt, int* __restrict__ offs, int* __restrict__ fboff,
    float* __restrict__ outF)
{
  __shared__ int sfb[NFB][8];
  __shared__ float pp[8][32];
  __shared__ float pe[8];
  __shared__ int cntS[8], offS[8];
  int t = threadIdx.x;
#pragma unroll
  for (int i = 0; i < 4; i++) {
    int idx = t + 256 * i;
    int fb = idx >> 3, e = idx & 7;
    int s = 0;
    for (int j = 0; j < 16; j++) s += bcnt[e * NBLK + fb * 16 + j];
    sfb[fb][e] = s;
  }
  {
    int e = t >> 5, ch = t & 31;
    float f = 0.f;
    for (int j = 0; j < 64; j++) f += psum[e * NBLK + ch * 64 + j];
    pp[e][ch] = f;
  }
  __syncthreads();
  if (t < 8) {
    float f = 0.f;
    for (int ch = 0; ch < 32; ch++) f += pp[t][ch];
    pe[t] = f;
    int c = 0;
    for (int fb = 0; fb < NFB; fb++) c += sfb[fb][t];
    cntS[t] = c;
    cnt[t] = c;
  }
  __syncthreads();
  if (t == 0) {
    int s = 0;
    for (int e = 0; e < 8; e++) { offS[e] = s; offs[e] = s; s += cntS[e]; }
    const float invN = 1.f / (float)NTOK;
    float acc = 0.f;
    for (int e = 0; e < 8; e++) acc += ((float)cntS[e] * invN) * (pe[e] * invN);
    outF[0] = (float)NEXP * acc;
  }
  __syncthreads();
  if (t < 8) {
    int run = offS[t];
    for (int fb = 0; fb < NFB; fb++) { fboff[fb * 8 + t] = run; run += sfb[fb][t]; }
  }
}

// ---------------- fill: ballot-rank slot assignment (deterministic) ----------------
__global__ __launch_bounds__(64) void k_fill(
    const int* __restrict__ topE, const int* __restrict__ fboff,
    int* __restrict__ tokof, int* __restrict__ destof)
{
  int lane = threadIdx.x;
  int blk = blockIdx.x;
  int n = blk * 64 + lane;
  int e0 = topE[2 * n], e1 = topE[2 * n + 1];
  u64 below = (1ull << lane) - 1ull;
  int slot0 = 0, slot1 = 0;
#pragma unroll
  for (int e = 0; e < 8; e++) {
    u64 m0 = __ballot(e0 == e);
    u64 m1 = __ballot(e1 == e);
    int c0 = __popcll(m0);
    int base = fboff[blk * 8 + e];
    if (e0 == e) slot0 = base + __popcll(m0 & below);
    if (e1 == e) slot1 = base + c0 + __popcll(m1 & below);
  }
  tokof[slot0] = n; destof[slot0] = 2 * n;
  tokof[slot1] = n; destof[slot1] = 2 * n + 1;
}

// ---------------- GEMM1: 128x64 tile, global_load_lds staging, dual-B SwiGLU ----------------
__global__ __launch_bounds__(256) void k_gemm1(
    const u16* __restrict__ xn, const u16* __restrict__ W1T, const u16* __restrict__ W3T,
    u16* __restrict__ act, const int* __restrict__ tokof,
    const int* __restrict__ cnt, const int* __restrict__ offs)
{
  int e = blockIdx.z;
  int cn = cnt[e];
  int mt = blockIdx.x;
  if (mt * 128 >= cn) return;
  int nb = blockIdx.y * 64;
  int off = offs[e];
  __shared__ __align__(16) short As[128 * 64];
  __shared__ __align__(16) short B1s[64 * 64];
  __shared__ __align__(16) short B3s[64 * 64];
  int t = threadIdx.x, lane = t & 63, w = t >> 6;
  int wr = w >> 1, wc = w & 1;
  int lr = lane >> 3, lc = lane & 7;
  int scol = (lc ^ lr) * 8;            // pre-swizzled source column (elements)

  const u16* srcA[4]; short* dstA[4];
#pragma unroll
  for (int i = 0; i < 4; i++) {
    int m = mt * 128 + w * 32 + i * 8 + lr;
    int tok = (m < cn) ? tokof[off + m] : 0;
    srcA[i] = xn + (size_t)tok * HD + scol;
    dstA[i] = As + (w * 32 + i * 8) * 64;
  }
  const u16 *srcB1[2], *srcB3[2]; short *dstB1[2], *dstB3[2];
#pragma unroll
  for (int j = 0; j < 2; j++) {
    int n = nb + w * 16 + j * 8 + lr;
    srcB1[j] = W1T + ((size_t)e * 512 + n) * HD + scol;
    srcB3[j] = W3T + ((size_t)e * 512 + n) * HD + scol;
    dstB1[j] = B1s + (w * 16 + j * 8) * 64;
    dstB3[j] = B3s + (w * 16 + j * 8) * 64;
  }
  int fr = lane & 15, fg = lane >> 4;
  int xorb = (fr & 7) << 4;
  int arow[4], brow[2];
#pragma unroll
  for (int fi = 0; fi < 4; fi++) arow[fi] = (wr * 64 + fi * 16 + fr) * 128;
#pragma unroll
  for (int fj = 0; fj < 2; fj++) brow[fj] = (wc * 32 + fj * 16 + fr) * 128;

  f32x4 z = {0.f, 0.f, 0.f, 0.f};
  f32x4 acc1[4][2], acc3[4][2];
#pragma unroll
  for (int i = 0; i < 4; i++)
#pragma unroll
    for (int j = 0; j < 2; j++) { acc1[i][j] = z; acc3[i][j] = z; }

  for (int kt = 0; kt < 8; kt++) {
#pragma unroll
    for (int i = 0; i < 4; i++) gload16(srcA[i], dstA[i]);
#pragma unroll
    for (int j = 0; j < 2; j++) { gload16(srcB1[j], dstB1[j]); gload16(srcB3[j], dstB3[j]); }
#pragma unroll
    for (int i = 0; i < 4; i++) srcA[i] += 64;
#pragma unroll
    for (int j = 0; j < 2; j++) { srcB1[j] += 64; srcB3[j] += 64; }
    __syncthreads();
#pragma unroll
    for (int kk = 0; kk < 2; kk++) {
      int kb = kk * 64 + fg * 16;
      bf16x8 af[4], b1f[2], b3f[2];
#pragma unroll
      for (int fi = 0; fi < 4; fi++)
        af[fi] = *(const bf16x8*)((const char*)As + arow[fi] + (kb ^ xorb));
#pragma unroll
      for (int fj = 0; fj < 2; fj++) {
        b1f[fj] = *(const bf16x8*)((const char*)B1s + brow[fj] + (kb ^ xorb));
        b3f[fj] = *(const bf16x8*)((const char*)B3s + brow[fj] + (kb ^ xorb));
      }
#pragma unroll
      for (int fi = 0; fi < 4; fi++)
#pragma unroll
        for (int fj = 0; fj < 2; fj++) {
          acc1[fi][fj] = __builtin_amdgcn_mfma_f32_16x16x32_bf16(af[fi], b1f[fj], acc1[fi][fj], 0, 0, 0);
          acc3[fi][fj] = __builtin_amdgcn_mfma_f32_16x16x32_bf16(af[fi], b3f[fj], acc3[fi][fj], 0, 0, 0);
        }
    }
    __syncthreads();
  }
#pragma unroll
  for (int fi = 0; fi < 4; fi++) {
#pragma unroll
    for (int r = 0; r < 4; r++) {
      int m = mt * 128 + wr * 64 + fi * 16 + fg * 4 + r;
      if (m < cn) {
        size_t rowbase = (size_t)(off + m) * HD;
#pragma unroll
        for (int fj = 0; fj < 2; fj++) {
          float a = acc1[fi][fj][r];
          float h3v = acc3[fi][fj][r];
          float v = a / (1.f + __expf(-a)) * h3v;
          act[rowbase + nb + wc * 32 + fj * 16 + fr] = f2bf(v);
        }
      }
    }
  }
}

// ---------------- GEMM2: 128x128 tile, global_load_lds staging, gate+scatter ----------------
__global__ __launch_bounds__(256) void k_gemm2(
    const u16* __restrict__ act, const u16* __restrict__ W2T,
    float* __restrict__ yp, const int* __restrict__ destof,
    const float* __restrict__ gates,
    const int* __restrict__ cnt, const int* __restrict__ offs)
{
  int e = blockIdx.z;
  int cn = cnt[e];
  int mt = blockIdx.x;
  if (mt * 128 >= cn) return;
  int nb = blockIdx.y * 128;
  int off = offs[e];
  __shared__ __align__(16) short As[128 * 64];
  __shared__ __align__(16) short Bs[128 * 64];
  int t = threadIdx.x, lane = t & 63, w = t >> 6;
  int wr = w >> 1, wc = w & 1;
  int lr = lane >> 3, lc = lane & 7;
  int scol = (lc ^ lr) * 8;

  const u16* srcA[4]; short* dstA[4];
#pragma unroll
  for (int i = 0; i < 4; i++) {
    int m = mt * 128 + w * 32 + i * 8 + lr;
    srcA[i] = act + (size_t)(off + ((m < cn) ? m : 0)) * HD + scol;
    dstA[i] = As + (w * 32 + i * 8) * 64;
  }
  const u16* srcB[4]; short* dstB[4];
#pragma unroll
  for (int i = 0; i < 4; i++) {
    int n = nb + w * 32 + i * 8 + lr;
    srcB[i] = W2T + ((size_t)e * 512 + n) * HD + scol;
    dstB[i] = Bs + (w * 32 + i * 8) * 64;
  }
  int fr = lane & 15, fg = lane >> 4;
  int xorb = (fr & 7) << 4;
  int arow[4], brow[4];
#pragma unroll
  for (int fi = 0; fi < 4; fi++) arow[fi] = (wr * 64 + fi * 16 + fr) * 128;
#pragma unroll
  for (int fj = 0; fj < 4; fj++) brow[fj] = (wc * 64 + fj * 16 + fr) * 128;

  f32x4 z = {0.f, 0.f, 0.f, 0.f};
  f32x4 acc[4][4];
#pragma unroll
  for (int i = 0; i < 4; i++)
#pragma unroll
    for (int j = 0; j < 4; j++) acc[i][j] = z;

  for (int kt = 0; kt < 8; kt++) {
#pragma unroll
    for (int i = 0; i < 4; i++) { gload16(srcA[i], dstA[i]); gload16(srcB[i], dstB[i]); }
#pragma unroll
    for (int i = 0; i < 4; i++) { srcA[i] += 64; srcB[i] += 64; }
    __syncthreads();
#pragma unroll
    for (int kk = 0; kk < 2; kk++) {
      int kb = kk * 64 + fg * 16;
      bf16x8 af[4], bf[4];
#pragma unroll
      for (int fi = 0; fi < 4; fi++)
        af[fi] = *(const bf16x8*)((const char*)As + arow[fi] + (kb ^ xorb));
#pragma unroll
      for (int fj = 0; fj < 4; fj++)
        bf[fj] = *(const bf16x8*)((const char*)Bs + brow[fj] + (kb ^ xorb));
#pragma unroll
      for (int fi = 0; fi < 4; fi++)
#pragma unroll
        for (int fj = 0; fj < 4; fj++)
          acc[fi][fj] = __builtin_amdgcn_mfma_f32_16x16x32_bf16(af[fi], bf[fj], acc[fi][fj], 0, 0, 0);
    }
    __syncthreads();
  }
#pragma unroll
  for (int fi = 0; fi < 4; fi++) {
#pragma unroll
    for (int r = 0; r < 4; r++) {
      int m = mt * 128 + wr * 64 + fi * 16 + fg * 4 + r;
      if (m < cn) {
        int dest = destof[off + m];
        float g = gates[dest];
        size_t rowbase = (size_t)dest * HD;
#pragma unroll
        for (int fj = 0; fj < 4; fj++)
          yp[rowbase + nb + wc * 64 + fj * 16 + fr] = g * acc[fi][fj][r];
      }
    }
  }
}

// ---------------- combine: out[n] = yp[2n] + yp[2n+1] ----------------
__global__ __launch_bounds__(256) void k_combine(
    const float* __restrict__ yp, float* __restrict__ out)
{
  int idx = blockIdx.x * 256 + threadIdx.x;
  int n = idx >> 7, c = idx & 127;
  const float4* yp4 = (const float4*)yp;
  float4 a = yp4[(size_t)(2 * n) * 128 + c];
  float4 b = yp4[(size_t)(2 * n + 1) * 128 + c];
  float4 o;
  o.x = a.x + b.x; o.y = a.y + b.y; o.z = a.z + b.z; o.w = a.w + b.w;
  ((float4*)out)[(size_t)n * 128 + c] = o;
}

extern "C" void kernel_launch(void* const* d_in, const int* in_sizes, int n_in,
                              void* d_out, int out_size, void* d_ws, size_t ws_size,
                              hipStream_t stream)
{
  const float* x  = (const float*)d_in[0];
  const float* Wg = (const float*)d_in[1];
  const float* W1 = (const float*)d_in[2];
  const float* W3 = (const float*)d_in[3];
  const float* W2 = (const float*)d_in[4];
  float* out = (float*)d_out;
  char* ws = (char*)d_ws;

  u16* W1T = (u16*)(ws + WS_W1T);
  u16* W3T = (u16*)(ws + WS_W3T);
  u16* W2T = (u16*)(ws + WS_W2T);
  u16* XN  = (u16*)(ws + WS_XN);
  u16* ACT = (u16*)(ws + WS_ACT);
  float* YP    = (float*)(ws + WS_YP);
  float* PSUM  = (float*)(ws + WS_PSUM);
  int* BCNT    = (int*)(ws + WS_BCNT);
  int* FBOFF   = (int*)(ws + WS_FBOFF);
  float* GATES = (float*)(ws + WS_GATES);
  int* TOKOF   = (int*)(ws + WS_TOKOF);
  int* DESTOF  = (int*)(ws + WS_DESTOF);
  int* TOPE    = (int*)(ws + WS_TOPE);
  int* CNT     = (int*)(ws + WS_CNT);
  int* OFFS    = (int*)(ws + WS_OFFS);

  k_prep<<<1536, 256, 0, stream>>>(W1, W3, W2, W1T, W3T, W2T);
  k_router<<<NBLK, 256, 0, stream>>>(x, Wg, XN, TOPE, GATES, PSUM, BCNT);
  k_scan<<<1, 256, 0, stream>>>(BCNT, PSUM, CNT, OFFS, FBOFF, out + 4194304);
  k_fill<<<NFB, 64, 0, stream>>>(TOPE, FBOFF, TOKOF, DESTOF);
  k_gemm1<<<dim3(64, 8, 8), 256, 0, stream>>>(XN, W1T, W3T, ACT, TOKOF, CNT, OFFS);
  k_gemm2<<<dim3(64, 4, 8), 256, 0, stream>>>(ACT, W2T, YP, DESTOF, GATES, CNT, OFFS);
  k_combine<<<4096, 256, 0, stream>>>(YP, out);
}

// Round 4
// 126.641 us; speedup vs baseline: 1.0381x; 1.0381x over previous
//
#include <hip/hip_runtime.h>

typedef unsigned short u16;
typedef unsigned int   u32;
typedef unsigned long long u64;
typedef __attribute__((ext_vector_type(8))) __bf16 bf16x8;
typedef __attribute__((ext_vector_type(4))) float  f32x4;

#define NTOK 8192
#define HD   512
#define NEXP 8
#define NBLK 2048   // router blocks (4 tokens each)
#define NFB  128    // fill blocks (64 tokens each)

// ---- workspace byte offsets ----
#define WS_W1T    0ull
#define WS_W3T    4194304ull
#define WS_W2T    8388608ull
#define WS_XN     12582912ull   // 8192*512 bf16
#define WS_ACT    20971520ull   // (16384+128)*512 bf16
#define WS_YP     37879808ull   // 16384*512 f32
#define WS_PSUM   71434240ull   // [8][2048] f32
#define WS_BCNT   71499776ull   // [8][2048] int
#define WS_FBOFF  71565312ull   // [128][8] int
#define WS_GATES  71696384ull   // 16384 f32
#define WS_TOKOF  71761920ull   // 16384 int
#define WS_DESTOF 71827456ull   // 16384 int
#define WS_TOPE   71892992ull   // 16384 int
#define WS_CNT    71958528ull   // 8 int
#define WS_OFFS   71958592ull   // 8 int

static __device__ __forceinline__ u16 f2bf(float f) {
  u32 u = __builtin_bit_cast(u32, f);
  u = (u + 0x7fffu + ((u >> 16) & 1u)) >> 16;
  return (u16)u;
}

static __device__ __forceinline__ void gload16(const void* g, void* l) {
  __builtin_amdgcn_global_load_lds((const __attribute__((address_space(1))) void*)g,
                                   (__attribute__((address_space(3))) void*)l, 16, 0, 0);
}

// ---------------- weight prep: f32 [e][k][n] -> bf16 [e][n][k], LDS transpose ----------------
__global__ __launch_bounds__(256) void k_prep(
    const float* __restrict__ W1, const float* __restrict__ W3, const float* __restrict__ W2,
    u16* __restrict__ W1T, u16* __restrict__ W3T, u16* __restrict__ W2T)
{
  u32 b = blockIdx.x;             // 1536 blocks = 3 arrays * 8 experts * 64 tiles
  u32 a = b >> 9;
  u32 rem = b & 511u;
  u32 e = rem >> 6;
  u32 tile = rem & 63u;
  u32 tk = tile >> 3, tn = tile & 7;
  const float* s = ((a == 0) ? W1 : (a == 1) ? W3 : W2) + ((size_t)e << 18);
  u16* d = ((a == 0) ? W1T : (a == 1) ? W3T : W2T) + ((size_t)e << 18);
  __shared__ u16 tileS[64 * 70];
  int t = threadIdx.x;
  int r = t >> 4, c4 = t & 15;
#pragma unroll
  for (int i = 0; i < 4; i++) {
    int rr = r + i * 16;
    const float4 v = *(const float4*)(s + (size_t)(tk * 64 + rr) * 512 + tn * 64 + c4 * 4);
    u32 w0 = f2bf(v.x) | ((u32)f2bf(v.y) << 16);
    u32 w1 = f2bf(v.z) | ((u32)f2bf(v.w) << 16);
    u32* p = (u32*)&tileS[rr * 70 + c4 * 4];
    p[0] = w0; p[1] = w1;
  }
  __syncthreads();
  int n = t >> 3, kc = t & 7;
#pragma unroll
  for (int i = 0; i < 2; i++) {
    int nn = n + i * 32;
    u16 vals[8];
#pragma unroll
    for (int j = 0; j < 8; j++) vals[j] = tileS[(kc * 8 + j) * 70 + nn];
    *(uint4*)(d + (size_t)(tn * 64 + nn) * 512 + tk * 64 + kc * 8) = *(uint4*)vals;
  }
}

// ---------------- router + RMSNorm (no global atomics) ----------------
__global__ __launch_bounds__(256) void k_router(
    const float* __restrict__ x, const float* __restrict__ Wg,
    u16* __restrict__ xn, int* __restrict__ topE, float* __restrict__ gates,
    float* __restrict__ psum, int* __restrict__ bcnt)
{
  __shared__ float lp[4][8];
  __shared__ int lcnt[8];
  int t = threadIdx.x;
  if (t < 8) lcnt[t] = 0;
  __syncthreads();
  int lane = t & 63;
  int w = t >> 6;
  int n = blockIdx.x * 4 + w;
  const float4* xr = (const float4*)(x + (size_t)n * HD);
  float4 xa = xr[lane * 2], xb = xr[lane * 2 + 1];
  float xv[8] = {xa.x, xa.y, xa.z, xa.w, xb.x, xb.y, xb.z, xb.w};
  float ss = 0.f;
  float le[8] = {0.f, 0.f, 0.f, 0.f, 0.f, 0.f, 0.f, 0.f};
  int base = lane * 8;
#pragma unroll
  for (int j = 0; j < 8; j++) {
    float v = xv[j];
    ss += v * v;
    const float4* wg = (const float4*)(Wg + (size_t)(base + j) * NEXP);
    float4 w0 = wg[0], w1 = wg[1];
    le[0] += v * w0.x; le[1] += v * w0.y; le[2] += v * w0.z; le[3] += v * w0.w;
    le[4] += v * w1.x; le[5] += v * w1.y; le[6] += v * w1.z; le[7] += v * w1.w;
  }
#pragma unroll
  for (int s = 1; s < 64; s <<= 1) {
    ss += __shfl_xor(ss, s);
#pragma unroll
    for (int e = 0; e < 8; e++) le[e] += __shfl_xor(le[e], s);
  }
  float m = le[0];
#pragma unroll
  for (int e = 1; e < 8; e++) m = fmaxf(m, le[e]);
  float p[8]; float S = 0.f;
#pragma unroll
  for (int e = 0; e < 8; e++) { p[e] = __expf(le[e] - m); S += p[e]; }
  float inv = 1.f / S;
#pragma unroll
  for (int e = 0; e < 8; e++) p[e] *= inv;
  int i1 = 0;
#pragma unroll
  for (int e = 1; e < 8; e++) if (p[e] > p[i1]) i1 = e;
  int i2 = (i1 == 0) ? 1 : 0;
#pragma unroll
  for (int e = 0; e < 8; e++) if (e != i1 && p[e] > p[i2]) i2 = e;

  if (lane < 8) lp[w][lane] = p[lane];
  if (lane == 0) {
    topE[2 * n] = i1; topE[2 * n + 1] = i2;
    float gs = p[i1] + p[i2];
    gates[2 * n] = p[i1] / gs;
    gates[2 * n + 1] = p[i2] / gs;
    atomicAdd(&lcnt[i1], 1);   // LDS atomic: deterministic value
    atomicAdd(&lcnt[i2], 1);
  }
  float rinv = rsqrtf(ss * (1.f / 512.f) + 1e-8f);
  uint4 o;
  u32* op = (u32*)&o;
#pragma unroll
  for (int j = 0; j < 4; j++) {
    u32 lo = f2bf(xv[2 * j] * rinv);
    u32 hi = f2bf(xv[2 * j + 1] * rinv);
    op[j] = lo | (hi << 16);
  }
  ((uint4*)(xn + (size_t)n * HD))[lane] = o;
  __syncthreads();
  if (t < 8) {
    bcnt[t * NBLK + blockIdx.x] = lcnt[t];
    psum[t * NBLK + blockIdx.x] = ((lp[0][t] + lp[1][t]) + lp[2][t]) + lp[3][t];
  }
}

// ---------------- scan: counts, offsets, fill-block offsets, load_F ----------------
__global__ __launch_bounds__(256) void k_scan(
    const int* __restrict__ bcnt, const float* __restrict__ psum,
    int* __restrict__ cnt, int* __restrict__ offs, int* __restrict__ fboff,
    float* __restrict__ outF)
{
  __shared__ int sfb[NFB][8];
  __shared__ float pp[8][32];
  __shared__ float pe[8];
  __shared__ int cntS[8], offS[8];
  int t = threadIdx.x;
#pragma unroll
  for (int i = 0; i < 4; i++) {
    int idx = t + 256 * i;
    int fb = idx >> 3, e = idx & 7;
    int s = 0;
    for (int j = 0; j < 16; j++) s += bcnt[e * NBLK + fb * 16 + j];
    sfb[fb][e] = s;
  }
  {
    int e = t >> 5, ch = t & 31;
    float f = 0.f;
    for (int j = 0; j < 64; j++) f += psum[e * NBLK + ch * 64 + j];
    pp[e][ch] = f;
  }
  __syncthreads();
  if (t < 8) {
    float f = 0.f;
    for (int ch = 0; ch < 32; ch++) f += pp[t][ch];
    pe[t] = f;
    int c = 0;
    for (int fb = 0; fb < NFB; fb++) c += sfb[fb][t];
    cntS[t] = c;
    cnt[t] = c;
  }
  __syncthreads();
  if (t == 0) {
    int s = 0;
    for (int e = 0; e < 8; e++) { offS[e] = s; offs[e] = s; s += cntS[e]; }
    const float invN = 1.f / (float)NTOK;
    float acc = 0.f;
    for (int e = 0; e < 8; e++) acc += ((float)cntS[e] * invN) * (pe[e] * invN);
    outF[0] = (float)NEXP * acc;
  }
  __syncthreads();
  if (t < 8) {
    int run = offS[t];
    for (int fb = 0; fb < NFB; fb++) { fboff[fb * 8 + t] = run; run += sfb[fb][t]; }
  }
}

// ---------------- fill: ballot-rank slot assignment (deterministic) ----------------
__global__ __launch_bounds__(64) void k_fill(
    const int* __restrict__ topE, const int* __restrict__ fboff,
    int* __restrict__ tokof, int* __restrict__ destof)
{
  int lane = threadIdx.x;
  int blk = blockIdx.x;
  int n = blk * 64 + lane;
  int e0 = topE[2 * n], e1 = topE[2 * n + 1];
  u64 below = (1ull << lane) - 1ull;
  int slot0 = 0, slot1 = 0;
#pragma unroll
  for (int e = 0; e < 8; e++) {
    u64 m0 = __ballot(e0 == e);
    u64 m1 = __ballot(e1 == e);
    int c0 = __popcll(m0);
    int base = fboff[blk * 8 + e];
    if (e0 == e) slot0 = base + __popcll(m0 & below);
    if (e1 == e) slot1 = base + c0 + __popcll(m1 & below);
  }
  tokof[slot0] = n; destof[slot0] = 2 * n;
  tokof[slot1] = n; destof[slot1] = 2 * n + 1;
}

// ---------------- GEMM1: 64x64 tile, 2-phase dbuf DMA staging, dual-B SwiGLU ----------------
__global__ __launch_bounds__(256) void k_gemm1(
    const u16* __restrict__ xn, const u16* __restrict__ W1T, const u16* __restrict__ W3T,
    u16* __restrict__ act, const int* __restrict__ tokof,
    const int* __restrict__ cnt, const int* __restrict__ offs)
{
  int e = blockIdx.z;
  int cn = cnt[e];
  int mt = blockIdx.x;
  if (mt * 64 >= cn) return;
  int nb = blockIdx.y * 64;
  int off = offs[e];
  // double-buffered: 2 x (A 4096 + B1 4096 + B3 4096) shorts = 48 KB
  __shared__ __align__(16) short As[2 * 4096];
  __shared__ __align__(16) short B1s[2 * 4096];
  __shared__ __align__(16) short B3s[2 * 4096];
  int t = threadIdx.x, lane = t & 63, w = t >> 6;
  int wr = w >> 1, wc = w & 1;
  int lr = lane >> 3, lc = lane & 7;
  int scol = (lc ^ lr) * 8;            // pre-swizzled source column (elements)

  // staging: per thread 2 A-rows, 2 B1-rows, 2 B3-rows (8 rows per wave-call)
  const u16* srcA[2]; const u16 *srcB1[2], *srcB3[2];
  int dstOff[2];
#pragma unroll
  for (int i = 0; i < 2; i++) {
    int rr = w * 16 + i * 8 + lr;      // 0..63
    int m = mt * 64 + rr;
    int tok = (m < cn) ? tokof[off + m] : 0;
    srcA[i] = xn + (size_t)tok * HD + scol;
    int n = nb + rr;
    srcB1[i] = W1T + ((size_t)e * 512 + n) * HD + scol;
    srcB3[i] = W3T + ((size_t)e * 512 + n) * HD + scol;
    dstOff[i] = (w * 16 + i * 8) * 64; // shorts
  }

  int fr = lane & 15, fg = lane >> 4;
  int xorb = (fr & 7) << 4;
  int arow[2], brow[2];
#pragma unroll
  for (int fi = 0; fi < 2; fi++) arow[fi] = (wr * 32 + fi * 16 + fr) * 128;  // bytes
#pragma unroll
  for (int fj = 0; fj < 2; fj++) brow[fj] = (wc * 32 + fj * 16 + fr) * 128;

  f32x4 z = {0.f, 0.f, 0.f, 0.f};
  f32x4 acc1[2][2], acc3[2][2];
#pragma unroll
  for (int i = 0; i < 2; i++)
#pragma unroll
    for (int j = 0; j < 2; j++) { acc1[i][j] = z; acc3[i][j] = z; }

  // prologue: stage tile 0 into buf 0
#pragma unroll
  for (int i = 0; i < 2; i++) {
    gload16(srcA[i],  As  + dstOff[i]);
    gload16(srcB1[i], B1s + dstOff[i]);
    gload16(srcB3[i], B3s + dstOff[i]);
    srcA[i] += 64; srcB1[i] += 64; srcB3[i] += 64;
  }
  __syncthreads();

  int buf = 0;
  for (int kt = 0; kt < 8; kt++) {
    if (kt < 7) {
      int bo = (buf ^ 1) * 4096;
#pragma unroll
      for (int i = 0; i < 2; i++) {
        gload16(srcA[i],  As  + bo + dstOff[i]);
        gload16(srcB1[i], B1s + bo + dstOff[i]);
        gload16(srcB3[i], B3s + bo + dstOff[i]);
        srcA[i] += 64; srcB1[i] += 64; srcB3[i] += 64;
      }
    }
    const char* Ab  = (const char*)As  + buf * 8192;
    const char* B1b = (const char*)B1s + buf * 8192;
    const char* B3b = (const char*)B3s + buf * 8192;
#pragma unroll
    for (int kk = 0; kk < 2; kk++) {
      int kb = kk * 64 + fg * 16;
      bf16x8 af[2], b1f[2], b3f[2];
#pragma unroll
      for (int fi = 0; fi < 2; fi++)
        af[fi] = *(const bf16x8*)(Ab + arow[fi] + (kb ^ xorb));
#pragma unroll
      for (int fj = 0; fj < 2; fj++) {
        b1f[fj] = *(const bf16x8*)(B1b + brow[fj] + (kb ^ xorb));
        b3f[fj] = *(const bf16x8*)(B3b + brow[fj] + (kb ^ xorb));
      }
#pragma unroll
      for (int fi = 0; fi < 2; fi++)
#pragma unroll
        for (int fj = 0; fj < 2; fj++) {
          acc1[fi][fj] = __builtin_amdgcn_mfma_f32_16x16x32_bf16(af[fi], b1f[fj], acc1[fi][fj], 0, 0, 0);
          acc3[fi][fj] = __builtin_amdgcn_mfma_f32_16x16x32_bf16(af[fi], b3f[fj], acc3[fi][fj], 0, 0, 0);
        }
    }
    __syncthreads();   // drains prefetch vmcnt(0) AFTER this tile's MFMA
    buf ^= 1;
  }
  // epilogue: act = silu(h1)*h3 -> bf16
#pragma unroll
  for (int fi = 0; fi < 2; fi++) {
#pragma unroll
    for (int r = 0; r < 4; r++) {
      int m = mt * 64 + wr * 32 + fi * 16 + fg * 4 + r;
      if (m < cn) {
        size_t rowbase = (size_t)(off + m) * HD;
#pragma unroll
        for (int fj = 0; fj < 2; fj++) {
          float a = acc1[fi][fj][r];
          float h3v = acc3[fi][fj][r];
          float v = a / (1.f + __expf(-a)) * h3v;
          act[rowbase + nb + wc * 32 + fj * 16 + fr] = f2bf(v);
        }
      }
    }
  }
}

// ---------------- GEMM2: 64x128 tile, 2-phase dbuf DMA staging, gate+scatter ----------------
__global__ __launch_bounds__(256) void k_gemm2(
    const u16* __restrict__ act, const u16* __restrict__ W2T,
    float* __restrict__ yp, const int* __restrict__ destof,
    const float* __restrict__ gates,
    const int* __restrict__ cnt, const int* __restrict__ offs)
{
  int e = blockIdx.z;
  int cn = cnt[e];
  int mt = blockIdx.x;
  if (mt * 64 >= cn) return;
  int nb = blockIdx.y * 128;
  int off = offs[e];
  // double-buffered: 2 x (A 4096 + B 8192) shorts = 48 KB
  __shared__ __align__(16) short As[2 * 4096];
  __shared__ __align__(16) short Bs[2 * 8192];
  int t = threadIdx.x, lane = t & 63, w = t >> 6;
  int wr = w >> 1, wc = w & 1;
  int lr = lane >> 3, lc = lane & 7;
  int scol = (lc ^ lr) * 8;

  const u16* srcA[2]; int dstOffA[2];
#pragma unroll
  for (int i = 0; i < 2; i++) {
    int rr = w * 16 + i * 8 + lr;
    int m = mt * 64 + rr;
    srcA[i] = act + (size_t)(off + ((m < cn) ? m : 0)) * HD + scol;
    dstOffA[i] = (w * 16 + i * 8) * 64;
  }
  const u16* srcB[4]; int dstOffB[4];
#pragma unroll
  for (int i = 0; i < 4; i++) {
    int rr = w * 32 + i * 8 + lr;      // 0..127
    int n = nb + rr;
    srcB[i] = W2T + ((size_t)e * 512 + n) * HD + scol;
    dstOffB[i] = (w * 32 + i * 8) * 64;
  }
  int fr = lane & 15, fg = lane >> 4;
  int xorb = (fr & 7) << 4;
  int arow[2], brow[4];
#pragma unroll
  for (int fi = 0; fi < 2; fi++) arow[fi] = (wr * 32 + fi * 16 + fr) * 128;
#pragma unroll
  for (int fj = 0; fj < 4; fj++) brow[fj] = (wc * 64 + fj * 16 + fr) * 128;

  f32x4 z = {0.f, 0.f, 0.f, 0.f};
  f32x4 acc[2][4];
#pragma unroll
  for (int i = 0; i < 2; i++)
#pragma unroll
    for (int j = 0; j < 4; j++) acc[i][j] = z;

#pragma unroll
  for (int i = 0; i < 2; i++) { gload16(srcA[i], As + dstOffA[i]); srcA[i] += 64; }
#pragma unroll
  for (int i = 0; i < 4; i++) { gload16(srcB[i], Bs + dstOffB[i]); srcB[i] += 64; }
  __syncthreads();

  int buf = 0;
  for (int kt = 0; kt < 8; kt++) {
    if (kt < 7) {
      int boA = (buf ^ 1) * 4096, boB = (buf ^ 1) * 8192;
#pragma unroll
      for (int i = 0; i < 2; i++) { gload16(srcA[i], As + boA + dstOffA[i]); srcA[i] += 64; }
#pragma unroll
      for (int i = 0; i < 4; i++) { gload16(srcB[i], Bs + boB + dstOffB[i]); srcB[i] += 64; }
    }
    const char* Ab = (const char*)As + buf * 8192;
    const char* Bb = (const char*)Bs + buf * 16384;
#pragma unroll
    for (int kk = 0; kk < 2; kk++) {
      int kb = kk * 64 + fg * 16;
      bf16x8 af[2], bf[4];
#pragma unroll
      for (int fi = 0; fi < 2; fi++)
        af[fi] = *(const bf16x8*)(Ab + arow[fi] + (kb ^ xorb));
#pragma unroll
      for (int fj = 0; fj < 4; fj++)
        bf[fj] = *(const bf16x8*)(Bb + brow[fj] + (kb ^ xorb));
#pragma unroll
      for (int fi = 0; fi < 2; fi++)
#pragma unroll
        for (int fj = 0; fj < 4; fj++)
          acc[fi][fj] = __builtin_amdgcn_mfma_f32_16x16x32_bf16(af[fi], bf[fj], acc[fi][fj], 0, 0, 0);
    }
    __syncthreads();
    buf ^= 1;
  }
#pragma unroll
  for (int fi = 0; fi < 2; fi++) {
#pragma unroll
    for (int r = 0; r < 4; r++) {
      int m = mt * 64 + wr * 32 + fi * 16 + fg * 4 + r;
      if (m < cn) {
        int dest = destof[off + m];
        float g = gates[dest];
        size_t rowbase = (size_t)dest * HD;
#pragma unroll
        for (int fj = 0; fj < 4; fj++)
          yp[rowbase + nb + wc * 64 + fj * 16 + fr] = g * acc[fi][fj][r];
      }
    }
  }
}

// ---------------- combine: out[n] = yp[2n] + yp[2n+1] ----------------
__global__ __launch_bounds__(256) void k_combine(
    const float* __restrict__ yp, float* __restrict__ out)
{
  int idx = blockIdx.x * 256 + threadIdx.x;
  int n = idx >> 7, c = idx & 127;
  const float4* yp4 = (const float4*)yp;
  float4 a = yp4[(size_t)(2 * n) * 128 + c];
  float4 b = yp4[(size_t)(2 * n + 1) * 128 + c];
  float4 o;
  o.x = a.x + b.x; o.y = a.y + b.y; o.z = a.z + b.z; o.w = a.w + b.w;
  ((float4*)out)[(size_t)n * 128 + c] = o;
}

extern "C" void kernel_launch(void* const* d_in, const int* in_sizes, int n_in,
                              void* d_out, int out_size, void* d_ws, size_t ws_size,
                              hipStream_t stream)
{
  const float* x  = (const float*)d_in[0];
  const float* Wg = (const float*)d_in[1];
  const float* W1 = (const float*)d_in[2];
  const float* W3 = (const float*)d_in[3];
  const float* W2 = (const float*)d_in[4];
  float* out = (float*)d_out;
  char* ws = (char*)d_ws;

  u16* W1T = (u16*)(ws + WS_W1T);
  u16* W3T = (u16*)(ws + WS_W3T);
  u16* W2T = (u16*)(ws + WS_W2T);
  u16* XN  = (u16*)(ws + WS_XN);
  u16* ACT = (u16*)(ws + WS_ACT);
  float* YP    = (float*)(ws + WS_YP);
  float* PSUM  = (float*)(ws + WS_PSUM);
  int* BCNT    = (int*)(ws + WS_BCNT);
  int* FBOFF   = (int*)(ws + WS_FBOFF);
  float* GATES = (float*)(ws + WS_GATES);
  int* TOKOF   = (int*)(ws + WS_TOKOF);
  int* DESTOF  = (int*)(ws + WS_DESTOF);
  int* TOPE    = (int*)(ws + WS_TOPE);
  int* CNT     = (int*)(ws + WS_CNT);
  int* OFFS    = (int*)(ws + WS_OFFS);

  k_prep<<<1536, 256, 0, stream>>>(W1, W3, W2, W1T, W3T, W2T);
  k_router<<<NBLK, 256, 0, stream>>>(x, Wg, XN, TOPE, GATES, PSUM, BCNT);
  k_scan<<<1, 256, 0, stream>>>(BCNT, PSUM, CNT, OFFS, FBOFF, out + 4194304);
  k_fill<<<NFB, 64, 0, stream>>>(TOPE, FBOFF, TOKOF, DESTOF);
  k_gemm1<<<dim3(128, 8, 8), 256, 0, stream>>>(XN, W1T, W3T, ACT, TOKOF, CNT, OFFS);
  k_gemm2<<<dim3(128, 4, 8), 256, 0, stream>>>(ACT, W2T, YP, DESTOF, GATES, CNT, OFFS);
  k_combine<<<4096, 256, 0, stream>>>(YP, out);
}